// Round 1
// baseline (1492.705 us; speedup 1.0000x reference)
//
#include <hip/hip_runtime.h>
#include <hip/hip_bf16.h>
#include <math.h>

#define NPTS 8192
#define KNN  16
#define CDIM 256
#define HDIM 128
#define NCH  16
#define CHSZ (NPTS / NCH)   // 512 candidates per chunk
#define KT   32             // K-tile depth for GEMMs

// ---------------------------------------------------------------------------
// kNN phase 1: each thread handles (target i, candidate chunk ch of 512 pts),
// keeps the 16 smallest (d2, idx) pairs sorted ascending, writes them out.
// Candidate loads are wave-uniform (all lanes share j) -> broadcast via cache.
// ---------------------------------------------------------------------------
__global__ __launch_bounds__(256) void knn_p1(const float* __restrict__ pos,
                                              float* __restrict__ cd,
                                              int* __restrict__ ci) {
  int g  = blockIdx.x * 256 + threadIdx.x;
  int i  = g & (NPTS - 1);
  int ch = g >> 13;
  float xi = pos[3 * i], yi = pos[3 * i + 1], zi = pos[3 * i + 2];
  float sqi = xi * xi + yi * yi + zi * zi;

  float dist[16];
  int   idn[16];
#pragma unroll
  for (int s = 0; s < 16; ++s) { dist[s] = INFINITY; idn[s] = 0x7fffffff; }

  int jbeg = ch * CHSZ;
  for (int jj = 0; jj < CHSZ; ++jj) {
    int j = jbeg + jj;
    float xj = pos[3 * j], yj = pos[3 * j + 1], zj = pos[3 * j + 2];
    float sqj = xj * xj + yj * yj + zj * zj;
    float dot = xi * xj + yi * yj + zi * zj;
    float d2 = sqi + sqj - 2.0f * dot;
    if (d2 < dist[15]) {   // new idx always > stored idx, so ties never enter
      float dc = d2; int ic = j;
#pragma unroll
      for (int s = 0; s < 16; ++s) {
        bool sw = (dc < dist[s]) || (dc == dist[s] && ic < idn[s]);
        float od = dist[s]; int oi = idn[s];
        dist[s] = sw ? dc : od;  idn[s] = sw ? ic : oi;
        dc      = sw ? od : dc;  ic     = sw ? oi : ic;
      }
    }
  }
#pragma unroll
  for (int s = 0; s < 16; ++s) {
    cd[(ch * 16 + s) * NPTS + i] = dist[s];   // [ch][s][i] -> coalesced in i
    ci[(ch * 16 + s) * NPTS + i] = idn[s];
  }
}

// ---------------------------------------------------------------------------
// kNN phase 2: merge the 16 sorted 16-lists per target -> final top-16.
// Chunks processed in index order, so stored idx < new idx always holds and
// tie handling matches stable top_k (earlier index wins).
// ---------------------------------------------------------------------------
__global__ __launch_bounds__(256) void knn_p2(const float* __restrict__ cd,
                                              const int* __restrict__ ci,
                                              int* __restrict__ idx_out) {
  int i = blockIdx.x * 256 + threadIdx.x;
  float dist[16];
  int   idn[16];
#pragma unroll
  for (int s = 0; s < 16; ++s) { dist[s] = INFINITY; idn[s] = 0x7fffffff; }

  for (int ch = 0; ch < NCH; ++ch) {
#pragma unroll 1
    for (int s = 0; s < 16; ++s) {
      float d = cd[(ch * 16 + s) * NPTS + i];
      if (d >= dist[15]) break;              // sorted chunk: rest can't enter
      int j = ci[(ch * 16 + s) * NPTS + i];
      float dc = d; int ic = j;
#pragma unroll
      for (int t = 0; t < 16; ++t) {
        bool sw = (dc < dist[t]) || (dc == dist[t] && ic < idn[t]);
        float od = dist[t]; int oi = idn[t];
        dist[t] = sw ? dc : od;  idn[t] = sw ? ic : oi;
        dc      = sw ? od : dc;  ic     = sw ? oi : ic;
      }
    }
  }
#pragma unroll
  for (int s = 0; s < 16; ++s) idx_out[i * 16 + s] = idn[s];
}

// ---------------------------------------------------------------------------
// Generic fp32 GEMM: out[M][NCOLS] = act(A[M][Kdim] @ W[Kdim][NCOLS] + bias)
// Block: 256 thr, 64 rows, all NCOLS cols; micro-tile 8 rows x (NCOLS/32) cols.
// ACT: 0 = none, 1 = relu.
// ---------------------------------------------------------------------------
template <int NCOLS, int ACT>
__global__ __launch_bounds__(256) void gemm_bias_act(
    const float* __restrict__ A, int Kdim,
    const float* __restrict__ W,
    const float* __restrict__ bias,
    float* __restrict__ out) {
  constexpr int NJ = NCOLS / 32;
  __shared__ float As[64][KT];
  __shared__ float Ws[KT][NCOLS];

  int tid = threadIdx.x;
  int row0 = blockIdx.x * 64;
  int tr = tid >> 5, tc = tid & 31;
  int arow = tid >> 2;
  int adb = (tid & 3) * 8;

  float acc[8][NJ];
#pragma unroll
  for (int i = 0; i < 8; ++i)
#pragma unroll
    for (int j = 0; j < NJ; ++j) acc[i][j] = 0.0f;

  int ktiles = (Kdim + KT - 1) / KT;
  for (int kt = 0; kt < ktiles; ++kt) {
    int k0 = kt * KT;
    // stage A tile (guarded scalar loads handle Kdim=3)
#pragma unroll
    for (int q = 0; q < 8; ++q) {
      int d = adb + q, gk = k0 + d;
      As[arow][d] = (gk < Kdim) ? A[(size_t)(row0 + arow) * Kdim + gk] : 0.0f;
    }
    // stage W tile: contiguous rows, float4 flat copy with row guard
    constexpr int WV = (KT * NCOLS / 4) / 256;
    const float4* Wg = reinterpret_cast<const float4*>(W + (size_t)k0 * NCOLS);
#pragma unroll
    for (int q = 0; q < WV; ++q) {
      int e = q * 256 + tid;
      int d = (e * 4) / NCOLS;
      float4 v = make_float4(0.f, 0.f, 0.f, 0.f);
      if (k0 + d < Kdim) v = Wg[e];
      reinterpret_cast<float4*>(&Ws[0][0])[e] = v;
    }
    __syncthreads();
#pragma unroll 4
    for (int d = 0; d < KT; ++d) {
      float a[8];
#pragma unroll
      for (int i = 0; i < 8; ++i) a[i] = As[tr * 8 + i][d];
#pragma unroll
      for (int j = 0; j < NJ; ++j) {
        float b = Ws[d][tc + 32 * j];
#pragma unroll
        for (int i = 0; i < 8; ++i) acc[i][j] = fmaf(a[i], b, acc[i][j]);
      }
    }
    __syncthreads();
  }
#pragma unroll
  for (int j = 0; j < NJ; ++j) {
    int c = tc + 32 * j;
    float bv = bias[c];
#pragma unroll
    for (int i = 0; i < 8; ++i) {
      float v = acc[i][j] + bv;
      if (ACT == 1) v = fmaxf(v, 0.0f);
      out[(size_t)(row0 + tr * 8 + i) * NCOLS + c] = v;
    }
  }
}

// ---------------------------------------------------------------------------
// Fused conv kernel: block handles 4 targets (64 rows = 4 targets x 16 nbrs).
// m1[row][d] = relu(T[j_row][d] + rel_row . W1p[:,d]) staged per K-tile,
// then GEMM vs W2 with 8x8 micro-tiles, max over k, +b2, relu, write.
// ---------------------------------------------------------------------------
__global__ __launch_bounds__(256) void conv_gemm_max(
    const float* __restrict__ T,     // [NPTS][256]
    const float* __restrict__ pos,   // [NPTS][3]
    const int* __restrict__ idx,     // [NPTS][16]
    const float* __restrict__ W1p,   // [3][256]
    const float* __restrict__ W2,    // [256][256]
    const float* __restrict__ b2,    // [256]
    float* __restrict__ hout) {      // [NPTS][256]
  __shared__ float m1s[64][KT];
  __shared__ float W2s[KT][CDIM];
  __shared__ float W1ps[3][CDIM];
  __shared__ int   js[64];
  __shared__ float rls[64][3];

  int tid = threadIdx.x;
  int t0 = blockIdx.x * 4;

  if (tid < 64) {
    int tg = tid >> 4, k = tid & 15;
    int j = idx[(t0 + tg) * 16 + k];
    js[tid] = j;
    rls[tid][0] = pos[3 * j]     - pos[3 * (t0 + tg)];
    rls[tid][1] = pos[3 * j + 1] - pos[3 * (t0 + tg) + 1];
    rls[tid][2] = pos[3 * j + 2] - pos[3 * (t0 + tg) + 2];
  }
  for (int e = tid; e < 3 * CDIM; e += 256) (&W1ps[0][0])[e] = W1p[e];
  __syncthreads();

  int arow = tid >> 2;
  int adb = (tid & 3) * 8;
  int jrow = js[arow];
  float r0 = rls[arow][0], r1 = rls[arow][1], r2 = rls[arow][2];

  int tr = tid >> 5, tc = tid & 31;
  float acc[8][8];
#pragma unroll
  for (int i = 0; i < 8; ++i)
#pragma unroll
    for (int j = 0; j < 8; ++j) acc[i][j] = 0.0f;

  for (int kt = 0; kt < CDIM / KT; ++kt) {
    int k0 = kt * KT;
    // stage W2 tile (flat float4 copy)
    const float4* Wg = reinterpret_cast<const float4*>(W2 + (size_t)k0 * CDIM);
#pragma unroll
    for (int q = 0; q < 8; ++q)
      reinterpret_cast<float4*>(&W2s[0][0])[q * 256 + tid] = Wg[q * 256 + tid];
    // stage m1 tile: 8 entries per thread, float4 T loads
#pragma unroll
    for (int q = 0; q < 8; q += 4) {
      float4 tv = *reinterpret_cast<const float4*>(
          T + (size_t)jrow * CDIM + k0 + adb + q);
      float tvv[4] = {tv.x, tv.y, tv.z, tv.w};
#pragma unroll
      for (int x = 0; x < 4; ++x) {
        int d = adb + q + x, c = k0 + d;
        float v = tvv[x] + r0 * W1ps[0][c] + r1 * W1ps[1][c] + r2 * W1ps[2][c];
        m1s[arow][d] = fmaxf(v, 0.0f);
      }
    }
    __syncthreads();
#pragma unroll 4
    for (int d = 0; d < KT; ++d) {
      float a[8];
#pragma unroll
      for (int i = 0; i < 8; ++i) a[i] = m1s[tr * 8 + i][d];
#pragma unroll
      for (int j = 0; j < 8; ++j) {
        float bv = W2s[d][tc + 32 * j];
#pragma unroll
        for (int i = 0; i < 8; ++i) acc[i][j] = fmaf(a[i], bv, acc[i][j]);
      }
    }
    __syncthreads();
  }
  // max over neighbors: thread's 8 rows are all one target (tr pairs share it)
#pragma unroll
  for (int j = 0; j < 8; ++j) {
    float m = acc[0][j];
#pragma unroll
    for (int i = 1; i < 8; ++i) m = fmaxf(m, acc[i][j]);
    m = fmaxf(m, __shfl_xor(m, 32));
    if ((tr & 1) == 0) {
      int tg = tr >> 1;
      int c = tc + 32 * j;
      hout[(size_t)(t0 + tg) * CDIM + c] = fmaxf(m + b2[c], 0.0f);
    }
  }
}

// ---------------------------------------------------------------------------
// Final layer: out[r] = sigmoid(h2[r] . w3 + b3); one wave per row.
// ---------------------------------------------------------------------------
__global__ __launch_bounds__(64) void final_k(const float* __restrict__ h2,
                                              const float* __restrict__ w3,
                                              const float* __restrict__ b3,
                                              float* __restrict__ out) {
  int r = blockIdx.x, l = threadIdx.x;
  float s = h2[(size_t)r * HDIM + l] * w3[l] +
            h2[(size_t)r * HDIM + 64 + l] * w3[64 + l];
#pragma unroll
  for (int o = 32; o > 0; o >>= 1) s += __shfl_down(s, o);
  if (l == 0) out[r] = 1.0f / (1.0f + expf(-(s + b3[0])));
}

extern "C" void kernel_launch(void* const* d_in, const int* in_sizes, int n_in,
                              void* d_out, int out_size, void* d_ws,
                              size_t ws_size, hipStream_t stream) {
  const float* pos   = (const float*)d_in[0];
  const float* c1_W1 = (const float*)d_in[1];
  const float* c1_b1 = (const float*)d_in[2];
  const float* c1_W2 = (const float*)d_in[3];
  const float* c1_b2 = (const float*)d_in[4];
  const float* c2_W1 = (const float*)d_in[5];
  const float* c2_b1 = (const float*)d_in[6];
  const float* c2_W2 = (const float*)d_in[7];
  const float* c2_b2 = (const float*)d_in[8];
  const float* c3_W1 = (const float*)d_in[9];
  const float* c3_b1 = (const float*)d_in[10];
  const float* c3_W2 = (const float*)d_in[11];
  const float* c3_b2 = (const float*)d_in[12];
  const float* h_W1  = (const float*)d_in[13];
  const float* h_b1  = (const float*)d_in[14];
  const float* h_W2  = (const float*)d_in[15];
  const float* h_b2  = (const float*)d_in[16];
  const float* h_W3  = (const float*)d_in[17];
  const float* h_b3  = (const float*)d_in[18];
  float* out = (float*)d_out;

  char* w = (char*)d_ws;
  int*   p_idx = (int*)w;                              // 512 KB
  float* p_T   = (float*)(w + (size_t)(1 << 20));      // 8 MB
  float* p_hA  = (float*)(w + (size_t)9 * (1 << 20));  // 8 MB
  float* p_hB  = (float*)(w + (size_t)17 * (1 << 20)); // 8 MB
  float* p_cd  = p_T;                                  // knn scratch aliases T
  int*   p_ci  = (int*)p_hA;                           // knn scratch aliases hA

  // kNN graph
  knn_p1<<<(NPTS * NCH) / 256, 256, 0, stream>>>(pos, p_cd, p_ci);
  knn_p2<<<NPTS / 256, 256, 0, stream>>>(p_cd, p_ci, p_idx);

  // conv1: T = pos @ c1_W1[0:3] + b1 ; fused gather/rel/relu/GEMM/max
  gemm_bias_act<256, 0><<<NPTS / 64, 256, 0, stream>>>(pos, 3, c1_W1, c1_b1, p_T);
  conv_gemm_max<<<NPTS / 4, 256, 0, stream>>>(p_T, pos, p_idx,
                                              c1_W1 + 3 * 256, c1_W2, c1_b2, p_hA);
  // conv2
  gemm_bias_act<256, 0><<<NPTS / 64, 256, 0, stream>>>(p_hA, 256, c2_W1, c2_b1, p_T);
  conv_gemm_max<<<NPTS / 4, 256, 0, stream>>>(p_T, pos, p_idx,
                                              c2_W1 + 256 * 256, c2_W2, c2_b2, p_hB);
  // conv3
  gemm_bias_act<256, 0><<<NPTS / 64, 256, 0, stream>>>(p_hB, 256, c3_W1, c3_b1, p_T);
  conv_gemm_max<<<NPTS / 4, 256, 0, stream>>>(p_T, pos, p_idx,
                                              c3_W1 + 256 * 256, c3_W2, c3_b2, p_hA);
  // classifier
  gemm_bias_act<128, 1><<<NPTS / 64, 256, 0, stream>>>(p_hA, 256, h_W1, h_b1, p_hB);
  gemm_bias_act<128, 1><<<NPTS / 64, 256, 0, stream>>>(p_hB, 128, h_W2, h_b2, p_T);
  final_k<<<NPTS, 64, 0, stream>>>(p_T, h_W3, h_b3, out);

  (void)in_sizes; (void)n_in; (void)out_size; (void)ws_size;
}

// Round 2
// 853.695 us; speedup vs baseline: 1.7485x; 1.7485x over previous
//
#include <hip/hip_runtime.h>
#include <hip/hip_bf16.h>
#include <math.h>

#define NPTS 8192
#define CDIM 256
#define HDIM 128
#define KT   32

typedef __attribute__((ext_vector_type(8))) short bf16x8;
typedef __attribute__((ext_vector_type(4))) float f32x4;
typedef unsigned long long u64;

static __device__ __forceinline__ short f2bf(float f) {
  __hip_bfloat16 h = __float2bfloat16(f);
  return *reinterpret_cast<short*>(&h);
}

// ---------------------------------------------------------------------------
// Prep: pos4[i] = (x, y, z, x^2+y^2+z^2)
// ---------------------------------------------------------------------------
__global__ __launch_bounds__(256) void pos4_prep(const float* __restrict__ pos,
                                                 float4* __restrict__ pos4) {
  int i = blockIdx.x * 256 + threadIdx.x;
  float x = pos[3 * i], y = pos[3 * i + 1], z = pos[3 * i + 2];
  pos4[i] = make_float4(x, y, z, x * x + y * y + z * z);
}

// Prep: W2t[c][k] = bf16(W2[k][c])   (256x256)
__global__ __launch_bounds__(256) void w2t_prep(const float* __restrict__ W2,
                                                short* __restrict__ W2t) {
  int t = blockIdx.x * 256 + threadIdx.x;
  int c = t >> 8, k = t & 255;
  W2t[c * 256 + k] = f2bf(W2[k * 256 + c]);
}

// ---------------------------------------------------------------------------
// kNN phase 1: thread = (target i, chunk ch). Candidates staged in LDS.
// Keys packed (d2_bits<<32)|idx -> single u64 compare gives exact lexicographic
// (d2, idx) order incl. tie-break. d2 clamped to >=0 so bit order == value order.
// ---------------------------------------------------------------------------
template <int NCHT>
__global__ __launch_bounds__(256) void knn_p1(const float4* __restrict__ pos4,
                                              u64* __restrict__ cdi) {
  constexpr int CH = NPTS / NCHT;
  __shared__ float4 cand[CH];
  int ch = blockIdx.x >> 5;                       // 32 blocks per chunk
  int i  = ((blockIdx.x & 31) << 8) | threadIdx.x;
  for (int q = threadIdx.x; q < CH; q += 256) cand[q] = pos4[ch * CH + q];
  __syncthreads();

  float4 p = pos4[i];
  u64 best[16];
#pragma unroll
  for (int s = 0; s < 16; ++s) best[s] = ~0ULL;

  int jb = ch * CH;
  for (int jj = 0; jj < CH; ++jj) {
    float4 c = cand[jj];
    float dot = p.x * c.x + p.y * c.y + p.z * c.z;
    float d2 = fmaf(-2.0f, dot, p.w + c.w);
    d2 = fmaxf(d2, 0.0f);
    u64 key = ((u64)__float_as_uint(d2) << 32) | (unsigned)(jb + jj);
    if (key < best[15]) {
#pragma unroll
      for (int s = 0; s < 16; ++s) {
        bool sw = key < best[s];
        u64 old = best[s];
        best[s] = sw ? key : old;
        key     = sw ? old : key;
      }
    }
  }
#pragma unroll
  for (int s = 0; s < 16; ++s)
    cdi[(size_t)(ch * 16 + s) * NPTS + i] = best[s];
}

// kNN phase 2: merge NCHT sorted 16-lists (u64 keys) -> final top-16 indices.
template <int NCHT>
__global__ __launch_bounds__(256) void knn_p2(const u64* __restrict__ cdi,
                                              int* __restrict__ idx_out) {
  int i = blockIdx.x * 256 + threadIdx.x;
  u64 best[16];
#pragma unroll
  for (int s = 0; s < 16; ++s) best[s] = ~0ULL;

  for (int ch = 0; ch < NCHT; ++ch) {
#pragma unroll 1
    for (int s = 0; s < 16; ++s) {
      u64 key = cdi[(size_t)(ch * 16 + s) * NPTS + i];
      if (key >= best[15]) break;     // sorted chunk: rest can't enter
#pragma unroll
      for (int t = 0; t < 16; ++t) {
        bool sw = key < best[t];
        u64 old = best[t];
        best[t] = sw ? key : old;
        key     = sw ? old : key;
      }
    }
  }
#pragma unroll
  for (int s = 0; s < 16; ++s) idx_out[i * 16 + s] = (int)(unsigned)best[s];
}

// ---------------------------------------------------------------------------
// fp32 GEMM: out[M][NCOLS] = act(A[M][Kdim] @ W[Kdim][NCOLS] + bias [+ pos@W1p])
// ADDP fuses the rel-part row term: out += pos[row] . W1p[:,col]  (TU build).
// ---------------------------------------------------------------------------
template <int NCOLS, int ACT, int ADDP>
__global__ __launch_bounds__(256) void gemm_bias_act(
    const float* __restrict__ A, int Kdim,
    const float* __restrict__ W,
    const float* __restrict__ bias,
    const float* __restrict__ pos,
    const float* __restrict__ W1p,
    float* __restrict__ out) {
  constexpr int NJ = NCOLS / 32;
  __shared__ float As[64][KT];
  __shared__ float Ws[KT][NCOLS];

  int tid = threadIdx.x;
  int row0 = blockIdx.x * 64;
  int tr = tid >> 5, tc = tid & 31;
  int arow = tid >> 2;
  int adb = (tid & 3) * 8;

  float acc[8][NJ];
#pragma unroll
  for (int i = 0; i < 8; ++i)
#pragma unroll
    for (int j = 0; j < NJ; ++j) acc[i][j] = 0.0f;

  int ktiles = (Kdim + KT - 1) / KT;
  for (int kt = 0; kt < ktiles; ++kt) {
    int k0 = kt * KT;
#pragma unroll
    for (int q = 0; q < 8; ++q) {
      int d = adb + q, gk = k0 + d;
      As[arow][d] = (gk < Kdim) ? A[(size_t)(row0 + arow) * Kdim + gk] : 0.0f;
    }
    constexpr int WV = (KT * NCOLS / 4) / 256;
    const float4* Wg = reinterpret_cast<const float4*>(W + (size_t)k0 * NCOLS);
#pragma unroll
    for (int q = 0; q < WV; ++q) {
      int e = q * 256 + tid;
      int d = (e * 4) / NCOLS;
      float4 v = make_float4(0.f, 0.f, 0.f, 0.f);
      if (k0 + d < Kdim) v = Wg[e];
      reinterpret_cast<float4*>(&Ws[0][0])[e] = v;
    }
    __syncthreads();
#pragma unroll 4
    for (int d = 0; d < KT; ++d) {
      float a[8];
#pragma unroll
      for (int i = 0; i < 8; ++i) a[i] = As[tr * 8 + i][d];
#pragma unroll
      for (int j = 0; j < NJ; ++j) {
        float b = Ws[d][tc + 32 * j];
#pragma unroll
        for (int i = 0; i < 8; ++i) acc[i][j] = fmaf(a[i], b, acc[i][j]);
      }
    }
    __syncthreads();
  }

  float p0[8], p1[8], p2[8];
  if constexpr (ADDP) {
#pragma unroll
    for (int i = 0; i < 8; ++i) {
      int r = row0 + tr * 8 + i;
      p0[i] = pos[3 * r]; p1[i] = pos[3 * r + 1]; p2[i] = pos[3 * r + 2];
    }
  }
#pragma unroll
  for (int j = 0; j < NJ; ++j) {
    int c = tc + 32 * j;
    float bv = bias[c];
    float w0 = 0.f, w1 = 0.f, w2 = 0.f;
    if constexpr (ADDP) { w0 = W1p[c]; w1 = W1p[256 + c]; w2 = W1p[512 + c]; }
#pragma unroll
    for (int i = 0; i < 8; ++i) {
      float v = acc[i][j] + bv;
      if constexpr (ADDP) v += p0[i] * w0 + p1[i] * w1 + p2[i] * w2;
      if (ACT == 1) v = fmaxf(v, 0.0f);
      out[(size_t)(row0 + tr * 8 + i) * NCOLS + c] = v;
    }
  }
}

// ---------------------------------------------------------------------------
// MFMA conv: block = 4 targets (64 rows = 4 x 16 nbrs) x 256 cols, K=256.
// m1 = relu(TU[j] - U[i]) staged bf16 in XOR-swizzled LDS; B = W2^T bf16 from
// global (L2-resident). 4 waves x (4x4 frags of 16x16) x 8 K-steps.
// Epilogue: max over 16 nbr-rows (in-frag + shfl), +b2, relu.
// ---------------------------------------------------------------------------
__global__ __launch_bounds__(256) void conv_mfma(
    const float* __restrict__ TU,    // [NPTS][256] = h@W1a + b1 + pos@W1p
    const float* __restrict__ pos,
    const int* __restrict__ idx,
    const float* __restrict__ W1p,   // [3][256]
    const short* __restrict__ W2t,   // bf16 [256][256] = W2^T
    const float* __restrict__ b2,
    float* __restrict__ hout) {
  __shared__ __align__(16) short m1s[64 * 256];
  __shared__ float Ub[4][256];
  __shared__ int js[64];

  int tid = threadIdx.x;
  int t0 = blockIdx.x * 4;
  if (tid < 64) js[tid] = idx[(t0 + (tid >> 4)) * 16 + (tid & 15)];
#pragma unroll
  for (int q = 0; q < 4; ++q) {
    int e = tid + 256 * q;
    int tg = e >> 8, c = e & 255;
    float x = pos[3 * (t0 + tg)], y = pos[3 * (t0 + tg) + 1],
          z = pos[3 * (t0 + tg) + 2];
    Ub[tg][c] = x * W1p[c] + y * W1p[256 + c] + z * W1p[512 + c];
  }
  __syncthreads();

  {
    int row = tid & 63;
    int wq = tid >> 6;
    int jrow = js[row];
    const float* TUj = TU + (size_t)jrow * 256;
    const float* Ui = &Ub[row >> 4][0];
#pragma unroll
    for (int q = 0; q < 8; ++q) {
      int c0 = wq * 8 + q * 32;
      float4 a = *reinterpret_cast<const float4*>(TUj + c0);
      float4 b = *reinterpret_cast<const float4*>(TUj + c0 + 4);
      float4 ua = *reinterpret_cast<const float4*>(Ui + c0);
      float4 ub = *reinterpret_cast<const float4*>(Ui + c0 + 4);
      bf16x8 o;
      o[0] = f2bf(fmaxf(a.x - ua.x, 0.f));
      o[1] = f2bf(fmaxf(a.y - ua.y, 0.f));
      o[2] = f2bf(fmaxf(a.z - ua.z, 0.f));
      o[3] = f2bf(fmaxf(a.w - ua.w, 0.f));
      o[4] = f2bf(fmaxf(b.x - ub.x, 0.f));
      o[5] = f2bf(fmaxf(b.y - ub.y, 0.f));
      o[6] = f2bf(fmaxf(b.z - ub.z, 0.f));
      o[7] = f2bf(fmaxf(b.w - ub.w, 0.f));
      int byte = row * 512 + c0 * 2;
      byte ^= (row & 7) << 4;                      // G4 XOR swizzle
      *reinterpret_cast<bf16x8*>(reinterpret_cast<char*>(m1s) + byte) = o;
    }
  }
  __syncthreads();

  int l = tid & 63, w = tid >> 6;
  int lhi = l >> 4, llo = l & 15;
  f32x4 zero = {0.f, 0.f, 0.f, 0.f};
  f32x4 acc[4][4];
#pragma unroll
  for (int m = 0; m < 4; ++m)
#pragma unroll
    for (int n = 0; n < 4; ++n) acc[m][n] = zero;

#pragma unroll
  for (int ks = 0; ks < 8; ++ks) {
    int k0 = ks * 32;
    bf16x8 af[4], bfr[4];
#pragma unroll
    for (int m = 0; m < 4; ++m) {
      int r = m * 16 + llo;
      int byte = r * 512 + k0 * 2 + lhi * 16;
      byte ^= (r & 7) << 4;
      af[m] = *reinterpret_cast<const bf16x8*>(
          reinterpret_cast<const char*>(m1s) + byte);
    }
#pragma unroll
    for (int n = 0; n < 4; ++n) {
      int c = w * 64 + n * 16 + llo;
      bfr[n] = *reinterpret_cast<const bf16x8*>(W2t + (size_t)c * 256 + k0 + lhi * 8);
    }
#pragma unroll
    for (int m = 0; m < 4; ++m)
#pragma unroll
      for (int n = 0; n < 4; ++n)
        acc[m][n] = __builtin_amdgcn_mfma_f32_16x16x32_bf16(af[m], bfr[n],
                                                            acc[m][n], 0, 0, 0);
  }

#pragma unroll
  for (int m = 0; m < 4; ++m)
#pragma unroll
    for (int n = 0; n < 4; ++n) {
      float v = fmaxf(fmaxf(acc[m][n][0], acc[m][n][1]),
                      fmaxf(acc[m][n][2], acc[m][n][3]));
      v = fmaxf(v, __shfl_xor(v, 16));
      v = fmaxf(v, __shfl_xor(v, 32));
      if (lhi == 0) {
        int c = w * 64 + n * 16 + llo;
        hout[(size_t)(t0 + m) * CDIM + c] = fmaxf(v + b2[c], 0.0f);
      }
    }
}

// ---------------------------------------------------------------------------
// Final layer: out[r] = sigmoid(h2[r] . w3 + b3); one wave per row.
// ---------------------------------------------------------------------------
__global__ __launch_bounds__(64) void final_k(const float* __restrict__ h2,
                                              const float* __restrict__ w3,
                                              const float* __restrict__ b3,
                                              float* __restrict__ out) {
  int r = blockIdx.x, l = threadIdx.x;
  float s = h2[(size_t)r * HDIM + l] * w3[l] +
            h2[(size_t)r * HDIM + 64 + l] * w3[64 + l];
#pragma unroll
  for (int o = 32; o > 0; o >>= 1) s += __shfl_down(s, o);
  if (l == 0) out[r] = 1.0f / (1.0f + expf(-(s + b3[0])));
}

extern "C" void kernel_launch(void* const* d_in, const int* in_sizes, int n_in,
                              void* d_out, int out_size, void* d_ws,
                              size_t ws_size, hipStream_t stream) {
  const float* pos   = (const float*)d_in[0];
  const float* c1_W1 = (const float*)d_in[1];
  const float* c1_b1 = (const float*)d_in[2];
  const float* c1_W2 = (const float*)d_in[3];
  const float* c1_b2 = (const float*)d_in[4];
  const float* c2_W1 = (const float*)d_in[5];
  const float* c2_b1 = (const float*)d_in[6];
  const float* c2_W2 = (const float*)d_in[7];
  const float* c2_b2 = (const float*)d_in[8];
  const float* c3_W1 = (const float*)d_in[9];
  const float* c3_b1 = (const float*)d_in[10];
  const float* c3_W2 = (const float*)d_in[11];
  const float* c3_b2 = (const float*)d_in[12];
  const float* h_W1  = (const float*)d_in[13];
  const float* h_b1  = (const float*)d_in[14];
  const float* h_W2  = (const float*)d_in[15];
  const float* h_b2  = (const float*)d_in[16];
  const float* h_W3  = (const float*)d_in[17];
  const float* h_b3  = (const float*)d_in[18];
  float* out = (float*)d_out;

  char* w = (char*)d_ws;
  const size_t MB = 1 << 20;
  int*    p_idx  = (int*)w;                         // [0, 512K)
  float4* p_pos4 = (float4*)(w + 512 * 1024);       // 128K
  short*  p_W2t1 = (short*)(w + 640 * 1024);        // 128K each
  short*  p_W2t2 = (short*)(w + 768 * 1024);
  short*  p_W2t3 = (short*)(w + 896 * 1024);
  u64*    p_cdi  = (u64*)(w + 1 * MB);              // 16MB (NCH16) / 32MB (NCH32)
  float*  p_TU   = (float*)(w + 1 * MB);            // 8MB  (after knn done)
  float*  p_hA   = (float*)(w + 9 * MB);            // 8MB
  float*  p_hB   = (float*)(w + 17 * MB);           // 8MB
  float*  p_c1   = (float*)(w + 1 * MB);            // 4MB (after conv3)
  float*  p_c2   = (float*)(w + 5 * MB);            // 4MB

  pos4_prep<<<NPTS / 256, 256, 0, stream>>>(pos, p_pos4);
  w2t_prep<<<256, 256, 0, stream>>>(c1_W2, p_W2t1);
  w2t_prep<<<256, 256, 0, stream>>>(c2_W2, p_W2t2);
  w2t_prep<<<256, 256, 0, stream>>>(c3_W2, p_W2t3);

  if (ws_size >= (size_t)34 * MB) {
    knn_p1<32><<<NPTS * 32 / 256, 256, 0, stream>>>(p_pos4, p_cdi);
    knn_p2<32><<<NPTS / 256, 256, 0, stream>>>(p_cdi, p_idx);
  } else {
    knn_p1<16><<<NPTS * 16 / 256, 256, 0, stream>>>(p_pos4, p_cdi);
    knn_p2<16><<<NPTS / 256, 256, 0, stream>>>(p_cdi, p_idx);
  }

  // conv1 (h = pos, K=3)
  gemm_bias_act<256, 0, 1><<<NPTS / 64, 256, 0, stream>>>(
      pos, 3, c1_W1, c1_b1, pos, c1_W1 + 3 * 256, p_TU);
  conv_mfma<<<NPTS / 4, 256, 0, stream>>>(p_TU, pos, p_idx, c1_W1 + 3 * 256,
                                          p_W2t1, c1_b2, p_hA);
  // conv2
  gemm_bias_act<256, 0, 1><<<NPTS / 64, 256, 0, stream>>>(
      p_hA, 256, c2_W1, c2_b1, pos, c2_W1 + 256 * 256, p_TU);
  conv_mfma<<<NPTS / 4, 256, 0, stream>>>(p_TU, pos, p_idx, c2_W1 + 256 * 256,
                                          p_W2t2, c2_b2, p_hB);
  // conv3
  gemm_bias_act<256, 0, 1><<<NPTS / 64, 256, 0, stream>>>(
      p_hB, 256, c3_W1, c3_b1, pos, c3_W1 + 256 * 256, p_TU);
  conv_mfma<<<NPTS / 4, 256, 0, stream>>>(p_TU, pos, p_idx, c3_W1 + 256 * 256,
                                          p_W2t3, c3_b2, p_hA);
  // classifier
  gemm_bias_act<128, 1, 0><<<NPTS / 64, 256, 0, stream>>>(
      p_hA, 256, h_W1, h_b1, nullptr, nullptr, p_c1);
  gemm_bias_act<128, 1, 0><<<NPTS / 64, 256, 0, stream>>>(
      p_c1, 128, h_W2, h_b2, nullptr, nullptr, p_c2);
  final_k<<<NPTS, 64, 0, stream>>>(p_c2, h_W3, h_b3, out);

  (void)in_sizes; (void)n_in; (void)out_size;
}

// Round 3
// 720.419 us; speedup vs baseline: 2.0720x; 1.1850x over previous
//
#include <hip/hip_runtime.h>
#include <hip/hip_bf16.h>
#include <math.h>

#define NPTS 8192
#define CDIM 256
#define HDIM 128
#define KT   32

typedef __attribute__((ext_vector_type(8))) short bf16x8;
typedef __attribute__((ext_vector_type(4))) float f32x4;
typedef unsigned long long u64;

static __device__ __forceinline__ short f2bf(float f) {
  __hip_bfloat16 h = __float2bfloat16(f);
  return *reinterpret_cast<short*>(&h);
}

// ---------------------------------------------------------------------------
// Prep: pos4[i] = (x, y, z, x^2+y^2+z^2)
// ---------------------------------------------------------------------------
__global__ __launch_bounds__(256) void pos4_prep(const float* __restrict__ pos,
                                                 float4* __restrict__ pos4) {
  int i = blockIdx.x * 256 + threadIdx.x;
  float x = pos[3 * i], y = pos[3 * i + 1], z = pos[3 * i + 2];
  pos4[i] = make_float4(x, y, z, x * x + y * y + z * z);
}

// ---------------------------------------------------------------------------
// Prep: fragment-major bf16 W2 so conv_mfma B-loads are wave-contiguous.
// w2f[((w*8+ks)*4+n)*512 + l*8 + q] = bf16(W2[ks*32+(l>>4)*8+q][w*64+n*16+(l&15)])
// ---------------------------------------------------------------------------
__global__ __launch_bounds__(256) void w2f_prep(const float* __restrict__ W2,
                                                short* __restrict__ w2f) {
  int t = blockIdx.x * 256 + threadIdx.x;   // 65536 elements
  int q = t & 7, l = (t >> 3) & 63, n = (t >> 9) & 3,
      ks = (t >> 11) & 7, w = (t >> 14) & 3;
  int k = ks * 32 + ((l >> 4) << 3) + q;
  int c = w * 64 + n * 16 + (l & 15);
  w2f[t] = f2bf(W2[k * 256 + c]);
}

// insertion step on named u64 registers (sorted ascending, b15 = largest)
#define KSTEP(s) { bool sw_ = key < b##s; u64 t_ = b##s; \
                   b##s = sw_ ? key : t_; key = sw_ ? t_ : key; }
#define KCHAIN KSTEP(0) KSTEP(1) KSTEP(2) KSTEP(3) KSTEP(4) KSTEP(5) \
               KSTEP(6) KSTEP(7) KSTEP(8) KSTEP(9) KSTEP(10) KSTEP(11) \
               KSTEP(12) KSTEP(13) KSTEP(14) KSTEP(15)
#define KINIT u64 b0=~0ULL,b1=~0ULL,b2=~0ULL,b3=~0ULL,b4=~0ULL,b5=~0ULL, \
                  b6=~0ULL,b7=~0ULL,b8=~0ULL,b9=~0ULL,b10=~0ULL,b11=~0ULL, \
                  b12=~0ULL,b13=~0ULL,b14=~0ULL,b15=~0ULL;

// ---------------------------------------------------------------------------
// kNN phase 1: thread = (target i, chunk ch). Candidates staged in LDS.
// Top-16 kept in 16 named u64 registers (no scratch spill).
// Key = (d2_bits<<32)|idx -> exact lexicographic (d2, idx) order.
// ---------------------------------------------------------------------------
template <int NCHT>
__global__ __launch_bounds__(256, 4) void knn_p1(const float4* __restrict__ pos4,
                                                 u64* __restrict__ cdi) {
  constexpr int CH = NPTS / NCHT;
  constexpr int BPC = NPTS / 256;             // blocks per chunk = 32
  __shared__ float4 cand[CH];
  int ch = blockIdx.x / BPC;
  int i  = (blockIdx.x % BPC) * 256 + threadIdx.x;
  for (int q = threadIdx.x; q < CH; q += 256) cand[q] = pos4[ch * CH + q];
  __syncthreads();

  float4 p = pos4[i];
  KINIT
  int jb = ch * CH;
  for (int jj = 0; jj < CH; ++jj) {
    float4 c = cand[jj];
    float dot = p.x * c.x + p.y * c.y + p.z * c.z;
    float d2 = fmaf(-2.0f, dot, p.w + c.w);
    d2 = fmaxf(d2, 0.0f);
    u64 key = ((u64)__float_as_uint(d2) << 32) | (unsigned)(jb + jj);
    if (key < b15) { KCHAIN }
  }
  u64* dst = cdi + (size_t)ch * 16 * NPTS + i;
  dst[0*(size_t)NPTS]=b0;  dst[1*(size_t)NPTS]=b1;  dst[2*(size_t)NPTS]=b2;
  dst[3*(size_t)NPTS]=b3;  dst[4*(size_t)NPTS]=b4;  dst[5*(size_t)NPTS]=b5;
  dst[6*(size_t)NPTS]=b6;  dst[7*(size_t)NPTS]=b7;  dst[8*(size_t)NPTS]=b8;
  dst[9*(size_t)NPTS]=b9;  dst[10*(size_t)NPTS]=b10; dst[11*(size_t)NPTS]=b11;
  dst[12*(size_t)NPTS]=b12; dst[13*(size_t)NPTS]=b13; dst[14*(size_t)NPTS]=b14;
  dst[15*(size_t)NPTS]=b15;
}

// kNN phase 2: merge NCHT sorted 16-lists -> final top-16 indices.
template <int NCHT>
__global__ __launch_bounds__(256, 4) void knn_p2(const u64* __restrict__ cdi,
                                                 int* __restrict__ idx_out) {
  int i = blockIdx.x * 256 + threadIdx.x;
  KINIT
  for (int ch = 0; ch < NCHT; ++ch) {
    const u64* src = cdi + (size_t)ch * 16 * NPTS + i;
#pragma unroll 1
    for (int s = 0; s < 16; ++s) {
      u64 key = src[(size_t)s * NPTS];
      if (key >= b15) break;               // sorted chunk: rest can't enter
      KCHAIN
    }
  }
  int* o = idx_out + i * 16;
  o[0]=(int)(unsigned)b0;   o[1]=(int)(unsigned)b1;   o[2]=(int)(unsigned)b2;
  o[3]=(int)(unsigned)b3;   o[4]=(int)(unsigned)b4;   o[5]=(int)(unsigned)b5;
  o[6]=(int)(unsigned)b6;   o[7]=(int)(unsigned)b7;   o[8]=(int)(unsigned)b8;
  o[9]=(int)(unsigned)b9;   o[10]=(int)(unsigned)b10; o[11]=(int)(unsigned)b11;
  o[12]=(int)(unsigned)b12; o[13]=(int)(unsigned)b13; o[14]=(int)(unsigned)b14;
  o[15]=(int)(unsigned)b15;
}

// ---------------------------------------------------------------------------
// fp32 GEMM: out[M][NCOLS] = act(A[M][Kdim] @ W[Kdim][NCOLS] + bias [+ pos@W1p])
// 32 rows/block (grid = 256 -> fills all CUs), micro-tile 4 x (NCOLS/32).
// ---------------------------------------------------------------------------
template <int NCOLS, int ACT, int ADDP>
__global__ __launch_bounds__(256) void gemm_bias_act(
    const float* __restrict__ A, int Kdim,
    const float* __restrict__ W,
    const float* __restrict__ bias,
    const float* __restrict__ pos,
    const float* __restrict__ W1p,
    float* __restrict__ out) {
  constexpr int NJ = NCOLS / 32;
  __shared__ float As[32][KT];
  __shared__ float Ws[KT][NCOLS];

  int tid = threadIdx.x;
  int row0 = blockIdx.x * 32;
  int tr = tid >> 5, tc = tid & 31;
  int arow = tid >> 3;
  int adb = (tid & 7) * 4;

  float acc[4][NJ];
#pragma unroll
  for (int i = 0; i < 4; ++i)
#pragma unroll
    for (int j = 0; j < NJ; ++j) acc[i][j] = 0.0f;

  int ktiles = (Kdim + KT - 1) / KT;
  for (int kt = 0; kt < ktiles; ++kt) {
    int k0 = kt * KT;
#pragma unroll
    for (int q = 0; q < 4; ++q) {
      int d = adb + q, gk = k0 + d;
      As[arow][d] = (gk < Kdim) ? A[(size_t)(row0 + arow) * Kdim + gk] : 0.0f;
    }
    constexpr int WV = (KT * NCOLS / 4) / 256;
    const float4* Wg = reinterpret_cast<const float4*>(W + (size_t)k0 * NCOLS);
#pragma unroll
    for (int q = 0; q < WV; ++q) {
      int e = q * 256 + tid;
      int d = (e * 4) / NCOLS;
      float4 v = make_float4(0.f, 0.f, 0.f, 0.f);
      if (k0 + d < Kdim) v = Wg[e];
      reinterpret_cast<float4*>(&Ws[0][0])[e] = v;
    }
    __syncthreads();
#pragma unroll 4
    for (int d = 0; d < KT; ++d) {
      float a[4];
#pragma unroll
      for (int i = 0; i < 4; ++i) a[i] = As[tr * 4 + i][d];
#pragma unroll
      for (int j = 0; j < NJ; ++j) {
        float b = Ws[d][tc + 32 * j];
#pragma unroll
        for (int i = 0; i < 4; ++i) acc[i][j] = fmaf(a[i], b, acc[i][j]);
      }
    }
    __syncthreads();
  }

  float p0[4], p1[4], p2[4];
  if constexpr (ADDP) {
#pragma unroll
    for (int i = 0; i < 4; ++i) {
      int r = row0 + tr * 4 + i;
      p0[i] = pos[3 * r]; p1[i] = pos[3 * r + 1]; p2[i] = pos[3 * r + 2];
    }
  }
#pragma unroll
  for (int j = 0; j < NJ; ++j) {
    int c = tc + 32 * j;
    float bv = bias[c];
    float w0 = 0.f, w1 = 0.f, w2 = 0.f;
    if constexpr (ADDP) { w0 = W1p[c]; w1 = W1p[256 + c]; w2 = W1p[512 + c]; }
#pragma unroll
    for (int i = 0; i < 4; ++i) {
      float v = acc[i][j] + bv;
      if constexpr (ADDP) v += p0[i] * w0 + p1[i] * w1 + p2[i] * w2;
      if (ACT == 1) v = fmaxf(v, 0.0f);
      out[(size_t)(row0 + tr * 4 + i) * NCOLS + c] = v;
    }
  }
}

// ---------------------------------------------------------------------------
// MFMA conv: block = 4 targets (64 rows = 4 x 16 nbrs) x 256 cols, K=256.
// m1 = relu(TU[j] - U[i]) staged bf16 in XOR-swizzled LDS; B from w2f
// (fragment-major, wave-contiguous 1KB loads, L2-resident).
// Epilogue: max over 16 nbr-rows (in-frag + shfl), +b2, relu.
// ---------------------------------------------------------------------------
__global__ __launch_bounds__(256) void conv_mfma(
    const float* __restrict__ TU,    // [NPTS][256] = h@W1a + b1 + pos@W1p
    const float* __restrict__ pos,
    const int* __restrict__ idx,
    const float* __restrict__ W1p,   // [3][256]
    const short* __restrict__ w2f,   // bf16 fragment-major W2
    const float* __restrict__ b2,
    float* __restrict__ hout) {
  __shared__ __align__(16) short m1s[64 * 256];
  __shared__ float Ub[4][256];
  __shared__ int js[64];

  int tid = threadIdx.x;
  int t0 = blockIdx.x * 4;
  if (tid < 64) js[tid] = idx[(t0 + (tid >> 4)) * 16 + (tid & 15)];
#pragma unroll
  for (int q = 0; q < 4; ++q) {
    int e = tid + 256 * q;
    int tg = e >> 8, c = e & 255;
    float x = pos[3 * (t0 + tg)], y = pos[3 * (t0 + tg) + 1],
          z = pos[3 * (t0 + tg) + 2];
    Ub[tg][c] = x * W1p[c] + y * W1p[256 + c] + z * W1p[512 + c];
  }
  __syncthreads();

  {
    int row = tid & 63;
    int wq = tid >> 6;
    int jrow = js[row];
    const float* TUj = TU + (size_t)jrow * 256;
    const float* Ui = &Ub[row >> 4][0];
#pragma unroll
    for (int q = 0; q < 8; ++q) {
      int c0 = wq * 8 + q * 32;
      float4 a = *reinterpret_cast<const float4*>(TUj + c0);
      float4 b = *reinterpret_cast<const float4*>(TUj + c0 + 4);
      float4 ua = *reinterpret_cast<const float4*>(Ui + c0);
      float4 ub = *reinterpret_cast<const float4*>(Ui + c0 + 4);
      bf16x8 o;
      o[0] = f2bf(fmaxf(a.x - ua.x, 0.f));
      o[1] = f2bf(fmaxf(a.y - ua.y, 0.f));
      o[2] = f2bf(fmaxf(a.z - ua.z, 0.f));
      o[3] = f2bf(fmaxf(a.w - ua.w, 0.f));
      o[4] = f2bf(fmaxf(b.x - ub.x, 0.f));
      o[5] = f2bf(fmaxf(b.y - ub.y, 0.f));
      o[6] = f2bf(fmaxf(b.z - ub.z, 0.f));
      o[7] = f2bf(fmaxf(b.w - ub.w, 0.f));
      int byte = row * 512 + c0 * 2;
      byte ^= (row & 7) << 4;                      // G4 XOR swizzle
      *reinterpret_cast<bf16x8*>(reinterpret_cast<char*>(m1s) + byte) = o;
    }
  }
  __syncthreads();

  int l = tid & 63, w = tid >> 6;
  int lhi = l >> 4, llo = l & 15;
  f32x4 zero = {0.f, 0.f, 0.f, 0.f};
  f32x4 acc[4][4];
#pragma unroll
  for (int m = 0; m < 4; ++m)
#pragma unroll
    for (int n = 0; n < 4; ++n) acc[m][n] = zero;

  const bf16x8* Wf = reinterpret_cast<const bf16x8*>(w2f);
#pragma unroll
  for (int ks = 0; ks < 8; ++ks) {
    int k0 = ks * 32;
    bf16x8 af[4], bfr[4];
#pragma unroll
    for (int m = 0; m < 4; ++m) {
      int r = m * 16 + llo;
      int byte = r * 512 + k0 * 2 + lhi * 16;
      byte ^= (r & 7) << 4;
      af[m] = *reinterpret_cast<const bf16x8*>(
          reinterpret_cast<const char*>(m1s) + byte);
    }
#pragma unroll
    for (int n = 0; n < 4; ++n)
      bfr[n] = Wf[((w * 8 + ks) * 4 + n) * 64 + l];
#pragma unroll
    for (int m = 0; m < 4; ++m)
#pragma unroll
      for (int n = 0; n < 4; ++n)
        acc[m][n] = __builtin_amdgcn_mfma_f32_16x16x32_bf16(af[m], bfr[n],
                                                            acc[m][n], 0, 0, 0);
  }

#pragma unroll
  for (int m = 0; m < 4; ++m)
#pragma unroll
    for (int n = 0; n < 4; ++n) {
      float v = fmaxf(fmaxf(acc[m][n][0], acc[m][n][1]),
                      fmaxf(acc[m][n][2], acc[m][n][3]));
      v = fmaxf(v, __shfl_xor(v, 16));
      v = fmaxf(v, __shfl_xor(v, 32));
      if (lhi == 0) {
        int c = w * 64 + n * 16 + llo;
        hout[(size_t)(t0 + m) * CDIM + c] = fmaxf(v + b2[c], 0.0f);
      }
    }
}

// ---------------------------------------------------------------------------
// Final layer: out[r] = sigmoid(h2[r] . w3 + b3); one wave per row.
// ---------------------------------------------------------------------------
__global__ __launch_bounds__(64) void final_k(const float* __restrict__ h2,
                                              const float* __restrict__ w3,
                                              const float* __restrict__ b3,
                                              float* __restrict__ out) {
  int r = blockIdx.x, l = threadIdx.x;
  float s = h2[(size_t)r * HDIM + l] * w3[l] +
            h2[(size_t)r * HDIM + 64 + l] * w3[64 + l];
#pragma unroll
  for (int o = 32; o > 0; o >>= 1) s += __shfl_down(s, o);
  if (l == 0) out[r] = 1.0f / (1.0f + expf(-(s + b3[0])));
}

extern "C" void kernel_launch(void* const* d_in, const int* in_sizes, int n_in,
                              void* d_out, int out_size, void* d_ws,
                              size_t ws_size, hipStream_t stream) {
  const float* pos   = (const float*)d_in[0];
  const float* c1_W1 = (const float*)d_in[1];
  const float* c1_b1 = (const float*)d_in[2];
  const float* c1_W2 = (const float*)d_in[3];
  const float* c1_b2 = (const float*)d_in[4];
  const float* c2_W1 = (const float*)d_in[5];
  const float* c2_b1 = (const float*)d_in[6];
  const float* c2_W2 = (const float*)d_in[7];
  const float* c2_b2 = (const float*)d_in[8];
  const float* c3_W1 = (const float*)d_in[9];
  const float* c3_b1 = (const float*)d_in[10];
  const float* c3_W2 = (const float*)d_in[11];
  const float* c3_b2 = (const float*)d_in[12];
  const float* h_W1  = (const float*)d_in[13];
  const float* h_b1  = (const float*)d_in[14];
  const float* h_W2  = (const float*)d_in[15];
  const float* h_b2  = (const float*)d_in[16];
  const float* h_W3  = (const float*)d_in[17];
  const float* h_b3  = (const float*)d_in[18];
  float* out = (float*)d_out;

  char* w = (char*)d_ws;
  const size_t MB = 1 << 20;
  int*    p_idx  = (int*)w;                         // [0, 512K)
  float4* p_pos4 = (float4*)(w + 512 * 1024);       // 128K
  short*  p_W2f1 = (short*)(w + 640 * 1024);        // 128K each
  short*  p_W2f2 = (short*)(w + 768 * 1024);
  short*  p_W2f3 = (short*)(w + 896 * 1024);
  u64*    p_cdi  = (u64*)(w + 1 * MB);              // 16MB (NCH16) / 32MB (NCH32)
  float*  p_TU   = (float*)(w + 1 * MB);            // 8MB  (after knn done)
  float*  p_hA   = (float*)(w + 9 * MB);            // 8MB
  float*  p_hB   = (float*)(w + 17 * MB);           // 8MB
  float*  p_c1   = (float*)(w + 1 * MB);            // 4MB (after conv3)
  float*  p_c2   = (float*)(w + 5 * MB);            // 4MB

  pos4_prep<<<NPTS / 256, 256, 0, stream>>>(pos, p_pos4);
  w2f_prep<<<256, 256, 0, stream>>>(c1_W2, p_W2f1);
  w2f_prep<<<256, 256, 0, stream>>>(c2_W2, p_W2f2);
  w2f_prep<<<256, 256, 0, stream>>>(c3_W2, p_W2f3);

  if (ws_size >= (size_t)34 * MB) {
    knn_p1<32><<<NPTS * 32 / 256, 256, 0, stream>>>(p_pos4, p_cdi);
    knn_p2<32><<<NPTS / 256, 256, 0, stream>>>(p_cdi, p_idx);
  } else {
    knn_p1<16><<<NPTS * 16 / 256, 256, 0, stream>>>(p_pos4, p_cdi);
    knn_p2<16><<<NPTS / 256, 256, 0, stream>>>(p_cdi, p_idx);
  }

  // conv1 (h = pos, K=3)
  gemm_bias_act<256, 0, 1><<<NPTS / 32, 256, 0, stream>>>(
      pos, 3, c1_W1, c1_b1, pos, c1_W1 + 3 * 256, p_TU);
  conv_mfma<<<NPTS / 4, 256, 0, stream>>>(p_TU, pos, p_idx, c1_W1 + 3 * 256,
                                          p_W2f1, c1_b2, p_hA);
  // conv2
  gemm_bias_act<256, 0, 1><<<NPTS / 32, 256, 0, stream>>>(
      p_hA, 256, c2_W1, c2_b1, pos, c2_W1 + 256 * 256, p_TU);
  conv_mfma<<<NPTS / 4, 256, 0, stream>>>(p_TU, pos, p_idx, c2_W1 + 256 * 256,
                                          p_W2f2, c2_b2, p_hB);
  // conv3
  gemm_bias_act<256, 0, 1><<<NPTS / 32, 256, 0, stream>>>(
      p_hB, 256, c3_W1, c3_b1, pos, c3_W1 + 256 * 256, p_TU);
  conv_mfma<<<NPTS / 4, 256, 0, stream>>>(p_TU, pos, p_idx, c3_W1 + 256 * 256,
                                          p_W2f3, c3_b2, p_hA);
  // classifier
  gemm_bias_act<128, 1, 0><<<NPTS / 32, 256, 0, stream>>>(
      p_hA, 256, h_W1, h_b1, nullptr, nullptr, p_c1);
  gemm_bias_act<128, 1, 0><<<NPTS / 32, 256, 0, stream>>>(
      p_c1, 128, h_W2, h_b2, nullptr, nullptr, p_c2);
  final_k<<<NPTS, 64, 0, stream>>>(p_c2, h_W3, h_b3, out);

  (void)in_sizes; (void)n_in; (void)out_size;
}